// Round 2
// baseline (425.329 us; speedup 1.0000x reference)
//
#include <hip/hip_runtime.h>
#include <hip/hip_bf16.h>

typedef __bf16 bf16;
typedef __bf16 bf16x8 __attribute__((ext_vector_type(8)));
typedef __bf16 bf16x4 __attribute__((ext_vector_type(4)));
typedef float  f32x4  __attribute__((ext_vector_type(4)));

constexpr int BB = 2, C = 512, NN = 8192, CK = 128;

// ---------------- Kernel 1: QKV projection ----------------
__global__ __launch_bounds__(256) void k_qkv(
    const float* __restrict__ x,
    const float* __restrict__ Wq, const float* __restrict__ bq,
    const float* __restrict__ Wk, const float* __restrict__ bk,
    const float* __restrict__ Wv, const float* __restrict__ bv,
    bf16* __restrict__ qkv_ws)
{
    const int t = threadIdx.x;
    const int lane = t & 63, w = t >> 6;
    const int lr = lane & 15, lg = lane >> 4;
    const int n0 = blockIdx.x * 128;
    const int which = blockIdx.y;
    const int b = blockIdx.z;
    const float* W    = which == 0 ? Wq : (which == 1 ? Wk : Wv);
    const float* bias = which == 0 ? bq : (which == 1 ? bk : bv);
    bf16* out = qkv_ws + (size_t)which * BB * NN * CK;

    __shared__ __align__(16) char s_xT[128 * 64];
    __shared__ __align__(16) char s_w [128 * 64];

    f32x4 acc[2][8];
#pragma unroll
    for (int m = 0; m < 2; m++)
#pragma unroll
        for (int j = 0; j < 8; j++) acc[m][j] = (f32x4){0.f, 0.f, 0.f, 0.f};

    const float* xb = x + (size_t)b * C * NN;

    for (int kt = 0; kt < C; kt += 32) {
        __syncthreads();
        {
            int col4 = (t & 31) * 4;
            int rbase = t >> 5;
#pragma unroll
            for (int p = 0; p < 4; p++) {
                int c = rbase + p * 8;
                float4 v = *(const float4*)(xb + (size_t)(kt + c) * NN + n0 + col4);
                float vv[4] = {v.x, v.y, v.z, v.w};
#pragma unroll
                for (int j = 0; j < 4; j++) {
                    int tok = col4 + j;
                    int off = (tok * 64 + c * 2) ^ ((tok & 3) << 4);
                    *(bf16*)(s_xT + off) = (bf16)vv[j];
                }
            }
        }
        {
            int c4 = (t & 7) * 4;
            int obase = t >> 3;
#pragma unroll
            for (int p = 0; p < 4; p++) {
                int o = obase + p * 32;
                float4 v = *(const float4*)(W + (size_t)o * C + kt + c4);
                bf16x4 b4 = { (bf16)v.x, (bf16)v.y, (bf16)v.z, (bf16)v.w };
                int off = (o * 64 + c4 * 2) ^ ((o & 3) << 4);
                *(bf16x4*)(s_w + off) = b4;
            }
        }
        __syncthreads();
        bf16x8 af[2], bfr[8];
#pragma unroll
        for (int m = 0; m < 2; m++) {
            int row = w * 32 + m * 16 + lr;
            int off = (row * 64 + lg * 16) ^ ((row & 3) << 4);
            af[m] = *(const bf16x8*)(s_xT + off);
        }
#pragma unroll
        for (int j = 0; j < 8; j++) {
            int row = j * 16 + lr;
            int off = (row * 64 + lg * 16) ^ ((row & 3) << 4);
            bfr[j] = *(const bf16x8*)(s_w + off);
        }
#pragma unroll
        for (int m = 0; m < 2; m++)
#pragma unroll
            for (int j = 0; j < 8; j++)
                acc[m][j] = __builtin_amdgcn_mfma_f32_16x16x32_bf16(af[m], bfr[j], acc[m][j], 0, 0, 0);
    }
#pragma unroll
    for (int m = 0; m < 2; m++)
#pragma unroll
        for (int j = 0; j < 8; j++) {
            int o = j * 16 + lr;
            float bia = bias[o];
#pragma unroll
            for (int r = 0; r < 4; r++) {
                int tok = n0 + w * 32 + m * 16 + lg * 4 + r;
                out[((size_t)b * NN + tok) * CK + o] = (bf16)(acc[m][j][r] + bia);
            }
        }
}

// ---------------- Kernel 2: flash attention with KV-split ----------------
// grid (N/64, B, nsplit); each block: 64 Q rows x (N/nsplit) keys.
// Writes unnormalized partial O (f32) + per-row m,l to workspace.
__global__ __launch_bounds__(256, 4) void k_attn(
    const bf16* __restrict__ qkv_ws,
    float* __restrict__ Opart, float* __restrict__ Mw, float* __restrict__ Lw,
    int nsplit)
{
    const int t = threadIdx.x;
    const int lane = t & 63, w = t >> 6;
    const int lr = lane & 15, lg = lane >> 4;
    const int b = blockIdx.y;
    const int q0 = blockIdx.x * 64;
    const int split = blockIdx.z;
    const int kbeg = split * (NN / nsplit);
    const int kend = kbeg + (NN / nsplit);

    const bf16* qg = qkv_ws;
    const bf16* kg = qkv_ws + (size_t)BB * NN * CK;
    const bf16* vg = qkv_ws + (size_t)2 * BB * NN * CK;

    __shared__ __align__(16) char s_k[64 * 256];     // [key][dim], swz ((row&7)<<4)
    __shared__ __align__(16) char s_vt[128 * 128];   // [dim][key], swz (((d&7)^((d>>3)&7))<<4)
    __shared__ __align__(16) char s_p[4][16 * 128];  // per-wave [row][key], swz (((row>>2)&3)<<5)

    bf16x8 qf[4];
    {
        int qrow = q0 + w * 16 + lr;
        const bf16* qp = qg + ((size_t)b * NN + qrow) * CK;
#pragma unroll
        for (int ks = 0; ks < 4; ks++)
            qf[ks] = *(const bf16x8*)(qp + ks * 32 + lg * 8);
    }

    f32x4 oacc[8];
#pragma unroll
    for (int j = 0; j < 8; j++) oacc[j] = (f32x4){0.f, 0.f, 0.f, 0.f};
    float mrun[4], lrun[4];
#pragma unroll
    for (int r = 0; r < 4; r++) { mrun[r] = -1e30f; lrun[r] = 0.f; }

    const float scale = 0.08838834764831845f;  // 128^-0.5

    for (int k0 = kbeg; k0 < kend; k0 += 64) {
        __syncthreads();
        // stage K tile [64][128], vectorized b128 writes
        {
            int chunk = t & 15, row = t >> 4;
#pragma unroll
            for (int p = 0; p < 4; p++) {
                int kr = row + p * 16;
                bf16x8 v = *(const bf16x8*)(kg + ((size_t)b * NN + k0 + kr) * CK + chunk * 8);
                int off = (kr * 256 + chunk * 16) ^ ((kr & 7) << 4);
                *(bf16x8*)(s_k + off) = v;
            }
        }
        // stage V^T tile [128][64]: each thread handles 4 key-rows x 8 dims,
        // packs 4 keys per b64 write (8 writes instead of 32 scalars)
        {
            int chunk = t & 15;          // dim chunk: d0 = chunk*8
            int q4 = (t >> 4) * 4;       // key quad base
            int d0 = chunk * 8;
            bf16x8 v0 = *(const bf16x8*)(vg + ((size_t)b * NN + k0 + q4 + 0) * CK + d0);
            bf16x8 v1 = *(const bf16x8*)(vg + ((size_t)b * NN + k0 + q4 + 1) * CK + d0);
            bf16x8 v2 = *(const bf16x8*)(vg + ((size_t)b * NN + k0 + q4 + 2) * CK + d0);
            bf16x8 v3 = *(const bf16x8*)(vg + ((size_t)b * NN + k0 + q4 + 3) * CK + d0);
#pragma unroll
            for (int j = 0; j < 8; j++) {
                bf16x4 wv = { v0[j], v1[j], v2[j], v3[j] };
                int off = ((d0 + j) * 128 + q4 * 2) ^ ((j ^ (chunk & 7)) << 4);
                *(bf16x4*)(s_vt + off) = wv;
            }
        }
        __syncthreads();
        // S = (Q K^T) * scale
        f32x4 sa[4];
#pragma unroll
        for (int j = 0; j < 4; j++) sa[j] = (f32x4){0.f, 0.f, 0.f, 0.f};
#pragma unroll
        for (int ks = 0; ks < 4; ks++) {
#pragma unroll
            for (int j = 0; j < 4; j++) {
                int kr = j * 16 + lr;
                int off = (kr * 256 + (ks * 32 + lg * 8) * 2) ^ ((kr & 7) << 4);
                bf16x8 kf = *(const bf16x8*)(s_k + off);
                sa[j] = __builtin_amdgcn_mfma_f32_16x16x32_bf16(qf[ks], kf, sa[j], 0, 0, 0);
            }
        }
#pragma unroll
        for (int j = 0; j < 4; j++) sa[j] *= scale;
        // online softmax; lane's rows are lg*4 + r
#pragma unroll
        for (int r = 0; r < 4; r++) {
            float mx = fmaxf(fmaxf(sa[0][r], sa[1][r]), fmaxf(sa[2][r], sa[3][r]));
#pragma unroll
            for (int m = 8; m > 0; m >>= 1) mx = fmaxf(mx, __shfl_xor(mx, m));
            float mnew = fmaxf(mrun[r], mx);
            float corr = __expf(mrun[r] - mnew);
            mrun[r] = mnew;
            float psum = 0.f;
            bf16 pb[4];
#pragma unroll
            for (int j = 0; j < 4; j++) {
                float p = __expf(sa[j][r] - mnew);
                psum += p;
                pb[j] = (bf16)p;
            }
#pragma unroll
            for (int m = 8; m > 0; m >>= 1) psum += __shfl_xor(psum, m);
            lrun[r] = lrun[r] * corr + psum;
#pragma unroll
            for (int j = 0; j < 8; j++) oacc[j][r] *= corr;
            int prow = lg * 4 + r;
#pragma unroll
            for (int j = 0; j < 4; j++) {
                int off = (prow * 128 + (j * 16 + lr) * 2) ^ (((prow >> 2) & 3) << 5);
                *(bf16*)(s_p[w] + off) = pb[j];
            }
        }
        // O += P V
#pragma unroll
        for (int ks = 0; ks < 2; ks++) {
            int poff = (lr * 128 + (ks * 32 + lg * 8) * 2) ^ (((lr >> 2) & 3) << 5);
            bf16x8 pf = *(const bf16x8*)(s_p[w] + poff);
#pragma unroll
            for (int j = 0; j < 8; j++) {
                int d = j * 16 + lr;
                int voff = (d * 128 + (ks * 32 + lg * 8) * 2) ^ ((((d & 7) ^ ((d >> 3) & 7))) << 4);
                bf16x8 vf = *(const bf16x8*)(s_vt + voff);
                oacc[j] = __builtin_amdgcn_mfma_f32_16x16x32_bf16(pf, vf, oacc[j], 0, 0, 0);
            }
        }
    }
    // epilogue: write unnormalized partials + m,l
    {
        size_t obase = (((size_t)split * BB + b) * NN + q0 + w * 16);
#pragma unroll
        for (int j = 0; j < 8; j++)
#pragma unroll
            for (int r = 0; r < 4; r++) {
                int row = lg * 4 + r;
                Opart[(obase + row) * CK + j * 16 + lr] = oacc[j][r];
            }
        if (lr == 0) {
#pragma unroll
            for (int r = 0; r < 4; r++) {
                Mw[obase + lg * 4 + r] = mrun[r];
                Lw[obase + lg * 4 + r] = lrun[r];
            }
        }
    }
}

// ---------------- Kernel 2b: combine KV-split partials ----------------
__global__ __launch_bounds__(256) void k_combine(
    const float* __restrict__ Opart, const float* __restrict__ Mw,
    const float* __restrict__ Lw, bf16* __restrict__ ao, int nsplit)
{
    const int t = threadIdx.x;
    const int b = blockIdx.y;
    const int r0 = blockIdx.x * 64;
    const int d4 = (t & 31) * 4;
#pragma unroll
    for (int p = 0; p < 8; p++) {
        int row = r0 + (t >> 5) + p * 8;
        size_t rbase = (size_t)b * NN + row;
        float M = -1e30f;
        for (int s = 0; s < nsplit; s++)
            M = fmaxf(M, Mw[((size_t)s * BB) * NN + rbase]);
        float L = 0.f;
        float4 acc = {0.f, 0.f, 0.f, 0.f};
        for (int s = 0; s < nsplit; s++) {
            size_t sb = ((size_t)s * BB) * NN + rbase;
            float wgt = __expf(Mw[sb] - M);
            L += Lw[sb] * wgt;
            float4 v = *(const float4*)(Opart + sb * CK + d4);
            acc.x += v.x * wgt; acc.y += v.y * wgt;
            acc.z += v.z * wgt; acc.w += v.w * wgt;
        }
        float inv = 1.f / L;
        bf16x4 o4 = { (bf16)(acc.x * inv), (bf16)(acc.y * inv),
                      (bf16)(acc.z * inv), (bf16)(acc.w * inv) };
        *(bf16x4*)(ao + rbase * CK + d4) = o4;
    }
}

// ---------------- Kernel 3: folded output projection + bias + residual ----------------
__global__ __launch_bounds__(256) void k_out(
    const float* __restrict__ x, const float* __restrict__ Wo, const float* __restrict__ bo,
    const bf16* __restrict__ ao, float* __restrict__ y)
{
    const int t = threadIdx.x;
    const int lane = t & 63, w = t >> 6;
    const int lr = lane & 15, lg = lane >> 4;
    const int n0 = blockIdx.x * 128;
    const int o0 = blockIdx.y * 64;
    const int b = blockIdx.z;

    __shared__ __align__(16) char s_w[64 * 256];
    __shared__ __align__(16) char s_a[128 * 256];

    {
        int c4 = (t & 31) * 4, rbase = t >> 5;
#pragma unroll
        for (int p = 0; p < 8; p++) {
            int row = rbase + p * 8;
            const float* wp = Wo + (size_t)(o0 + row) * C + c4;
            float4 a0 = *(const float4*)(wp);
            float4 a1 = *(const float4*)(wp + 128);
            float4 a2 = *(const float4*)(wp + 256);
            float4 a3 = *(const float4*)(wp + 384);
            bf16x4 r4 = { (bf16)(a0.x + a1.x + a2.x + a3.x), (bf16)(a0.y + a1.y + a2.y + a3.y),
                          (bf16)(a0.z + a1.z + a2.z + a3.z), (bf16)(a0.w + a1.w + a2.w + a3.w) };
            int off = (row * 256 + c4 * 2) ^ ((row & 7) << 4);
            *(bf16x4*)(s_w + off) = r4;
        }
    }
    {
        int chunk = t & 15, rbase = t >> 4;
#pragma unroll
        for (int p = 0; p < 8; p++) {
            int row = rbase + p * 16;
            bf16x8 v = *(const bf16x8*)(ao + ((size_t)b * NN + n0 + row) * CK + chunk * 8);
            int off = (row * 256 + chunk * 16) ^ ((row & 7) << 4);
            *(bf16x8*)(s_a + off) = v;
        }
    }
    __syncthreads();

    f32x4 acc[8];
#pragma unroll
    for (int j = 0; j < 8; j++) acc[j] = (f32x4){0.f, 0.f, 0.f, 0.f};
#pragma unroll
    for (int ks = 0; ks < 4; ks++) {
        int row = w * 16 + lr;
        int aoff = (row * 256 + (ks * 32 + lg * 8) * 2) ^ ((row & 7) << 4);
        bf16x8 wf = *(const bf16x8*)(s_w + aoff);
#pragma unroll
        for (int j = 0; j < 8; j++) {
            int nrow = j * 16 + lr;
            int boff = (nrow * 256 + (ks * 32 + lg * 8) * 2) ^ ((nrow & 7) << 4);
            bf16x8 af = *(const bf16x8*)(s_a + boff);
            acc[j] = __builtin_amdgcn_mfma_f32_16x16x32_bf16(wf, af, acc[j], 0, 0, 0);
        }
    }
#pragma unroll
    for (int j = 0; j < 8; j++) {
        int n = n0 + j * 16 + lr;
#pragma unroll
        for (int r = 0; r < 4; r++) {
            int o = o0 + w * 16 + lg * 4 + r;
            size_t idx = ((size_t)b * C + o) * NN + n;
            y[idx] = acc[j][r] + bo[o] + x[idx];
        }
    }
}

extern "C" void kernel_launch(void* const* d_in, const int* in_sizes, int n_in,
                              void* d_out, int out_size, void* d_ws, size_t ws_size,
                              hipStream_t stream)
{
    const float* x  = (const float*)d_in[0];
    const float* Wq = (const float*)d_in[1];
    const float* bq = (const float*)d_in[2];
    const float* Wk = (const float*)d_in[3];
    const float* bk = (const float*)d_in[4];
    const float* Wv = (const float*)d_in[5];
    const float* bv = (const float*)d_in[6];
    const float* Wo = (const float*)d_in[7];
    const float* bo = (const float*)d_in[8];
    float* y = (float*)d_out;

    const size_t qkv_elems = (size_t)3 * BB * NN * CK;   // bf16
    const size_t ao_elems  = (size_t)BB * NN * CK;       // bf16

    bf16* qkv = (bf16*)d_ws;
    bf16* ao  = qkv + qkv_elems;
    float* Opart = (float*)(ao + ao_elems);

    // choose split count by available workspace
    int nsplit = 4;
    {
        size_t fixed = (qkv_elems + ao_elems) * sizeof(bf16);
        size_t per_split = ((size_t)BB * NN * CK + 2 * (size_t)BB * NN) * sizeof(float);
        while (nsplit > 1 && fixed + (size_t)nsplit * per_split > ws_size) nsplit >>= 1;
    }
    float* Mw = Opart + (size_t)nsplit * BB * NN * CK;
    float* Lw = Mw + (size_t)nsplit * BB * NN;

    k_qkv<<<dim3(NN / 128, 3, BB), 256, 0, stream>>>(x, Wq, bq, Wk, bk, Wv, bv, qkv);
    k_attn<<<dim3(NN / 64, BB, nsplit), 256, 0, stream>>>(qkv, Opart, Mw, Lw, nsplit);
    k_combine<<<dim3(NN / 64, BB), 256, 0, stream>>>(Opart, Mw, Lw, ao, nsplit);
    k_out<<<dim3(NN / 128, C / 64, BB), 256, 0, stream>>>(x, Wo, bo, ao, y);
}

// Round 3
// 209.766 us; speedup vs baseline: 2.0276x; 2.0276x over previous
//
#include <hip/hip_runtime.h>
#include <hip/hip_bf16.h>

typedef __bf16 bf16;
typedef __bf16 bf16x8 __attribute__((ext_vector_type(8)));
typedef __bf16 bf16x4 __attribute__((ext_vector_type(4)));
typedef float  f32x4  __attribute__((ext_vector_type(4)));

constexpr int BB = 2, C = 512, NN = 8192, CK = 128;

// ---------------- Kernel 1: QKV projection ----------------
__global__ __launch_bounds__(256) void k_qkv(
    const float* __restrict__ x,
    const float* __restrict__ Wq, const float* __restrict__ bq,
    const float* __restrict__ Wk, const float* __restrict__ bk,
    const float* __restrict__ Wv, const float* __restrict__ bv,
    bf16* __restrict__ qkv_ws)
{
    const int t = threadIdx.x;
    const int lane = t & 63, w = t >> 6;
    const int lr = lane & 15, lg = lane >> 4;
    const int n0 = blockIdx.x * 128;
    const int which = blockIdx.y;
    const int b = blockIdx.z;
    const float* W    = which == 0 ? Wq : (which == 1 ? Wk : Wv);
    const float* bias = which == 0 ? bq : (which == 1 ? bk : bv);
    bf16* out = qkv_ws + (size_t)which * BB * NN * CK;

    __shared__ __align__(16) char s_xT[128 * 64];
    __shared__ __align__(16) char s_w [128 * 64];

    f32x4 acc[2][8];
#pragma unroll
    for (int m = 0; m < 2; m++)
#pragma unroll
        for (int j = 0; j < 8; j++) acc[m][j] = (f32x4){0.f, 0.f, 0.f, 0.f};

    const float* xb = x + (size_t)b * C * NN;

    for (int kt = 0; kt < C; kt += 32) {
        __syncthreads();
        {
            int col4 = (t & 31) * 4;
            int rbase = t >> 5;
#pragma unroll
            for (int p = 0; p < 4; p++) {
                int c = rbase + p * 8;
                float4 v = *(const float4*)(xb + (size_t)(kt + c) * NN + n0 + col4);
                float vv[4] = {v.x, v.y, v.z, v.w};
#pragma unroll
                for (int j = 0; j < 4; j++) {
                    int tok = col4 + j;
                    int off = (tok * 64 + c * 2) ^ ((tok & 3) << 4);
                    *(bf16*)(s_xT + off) = (bf16)vv[j];
                }
            }
        }
        {
            int c4 = (t & 7) * 4;
            int obase = t >> 3;
#pragma unroll
            for (int p = 0; p < 4; p++) {
                int o = obase + p * 32;
                float4 v = *(const float4*)(W + (size_t)o * C + kt + c4);
                bf16x4 b4 = { (bf16)v.x, (bf16)v.y, (bf16)v.z, (bf16)v.w };
                int off = (o * 64 + c4 * 2) ^ ((o & 3) << 4);
                *(bf16x4*)(s_w + off) = b4;
            }
        }
        __syncthreads();
        bf16x8 af[2], bfr[8];
#pragma unroll
        for (int m = 0; m < 2; m++) {
            int row = w * 32 + m * 16 + lr;
            int off = (row * 64 + lg * 16) ^ ((row & 3) << 4);
            af[m] = *(const bf16x8*)(s_xT + off);
        }
#pragma unroll
        for (int j = 0; j < 8; j++) {
            int row = j * 16 + lr;
            int off = (row * 64 + lg * 16) ^ ((row & 3) << 4);
            bfr[j] = *(const bf16x8*)(s_w + off);
        }
#pragma unroll
        for (int m = 0; m < 2; m++)
#pragma unroll
            for (int j = 0; j < 8; j++)
                acc[m][j] = __builtin_amdgcn_mfma_f32_16x16x32_bf16(af[m], bfr[j], acc[m][j], 0, 0, 0);
    }
#pragma unroll
    for (int m = 0; m < 2; m++)
#pragma unroll
        for (int j = 0; j < 8; j++) {
            int o = j * 16 + lr;
            float bia = bias[o];
#pragma unroll
            for (int r = 0; r < 4; r++) {
                int tok = n0 + w * 32 + m * 16 + lg * 4 + r;
                out[((size_t)b * NN + tok) * CK + o] = (bf16)(acc[m][j][r] + bia);
            }
        }
}

// ---------------- Kernel 2: flash attention, swapped-QK^T, 8 waves x 32q ----------------
// grid: 1D, 64*nsplit blocks; XCD-swizzled so each XCD owns one (b,split) KV range.
__global__ __launch_bounds__(512, 2) void k_attn(
    const bf16* __restrict__ qkv_ws,
    float* __restrict__ Opart, float* __restrict__ Mw, float* __restrict__ Lw,
    int nsplit)
{
    const int t = threadIdx.x;
    const int lane = t & 63, w = t >> 6;      // 8 waves
    const int lr = lane & 15, lg = lane >> 4;

    // XCD-aware bijective remap: consecutive rid per XCD
    int total = 64 * nsplit;
    int chunkv = total >> 3;
    int lin = blockIdx.x;
    int rid = (lin & 7) * chunkv + (lin >> 3);
    int qt = rid & 31;            // 32 q-tiles of 256
    int bs = rid >> 5;            // (b fast, split slow)
    int b = bs & 1, split = bs >> 1;

    const int q0 = qt * 256;
    const int kbeg = split * (NN / nsplit);
    const int kend = kbeg + (NN / nsplit);

    const bf16* qg = qkv_ws;
    const bf16* kg = qkv_ws + (size_t)BB * NN * CK;
    const bf16* vg = qkv_ws + (size_t)2 * BB * NN * CK;

    __shared__ __align__(16) char s_k[64 * 256];    // [key][dim] bf16, swz ((key&7)<<4)
    __shared__ __align__(16) char s_vt[128 * 128];  // [dim][key] bf16, swz (((d^(d>>3))&7)<<4)
    __shared__ __align__(16) char s_p[8 * 32 * 80]; // per-wave [q 32][key 64] bf16, 80B row stride

    char* s_pw = s_p + w * (32 * 80);

    const float scale = 0.08838834764831845f;   // 128^-0.5
    const float L2E = 1.4426950408889634f;

    // Q fragments, pre-scaled: qf[qm][ks] = Q[q0+w*32+qm*16+lr][ks*32+lg*8 ..+7] * scale
    bf16x8 qf[2][4];
    {
        int qbase = q0 + w * 32;
#pragma unroll
        for (int qm = 0; qm < 2; qm++) {
            const bf16* qp = qg + ((size_t)b * NN + qbase + qm * 16 + lr) * CK;
#pragma unroll
            for (int ks = 0; ks < 4; ks++) {
                bf16x8 v = *(const bf16x8*)(qp + ks * 32 + lg * 8);
#pragma unroll
                for (int i = 0; i < 8; i++) qf[qm][ks][i] = (bf16)((float)v[i] * scale);
            }
        }
    }

    f32x4 oacc[8][2];
#pragma unroll
    for (int dj = 0; dj < 8; dj++)
#pragma unroll
        for (int qm = 0; qm < 2; qm++) oacc[dj][qm] = (f32x4){0.f, 0.f, 0.f, 0.f};
    float mrun[2] = {0.f, 0.f};
    float lrun[2] = {0.f, 0.f};   // per-lane partial sums

    // staging role per wave: waves 0-3 stage K tile, 4-7 stage V^T tile
    bf16x8 stg[4];
    const int sk_chunk = t & 15;        // for K-threads
    const int sk_rowb  = t >> 4;        // 0..15 (only t<256)
    const int sv_chunk = t & 15;        // dim chunk for V-threads
    const int sv_q4    = ((t - 256) >> 4) * 4;  // 0..60 (only t>=256)

    auto issue_loads = [&](int k0) {
        if (w < 4) {
            const bf16* kp = kg + ((size_t)b * NN + k0 + sk_rowb) * CK + sk_chunk * 8;
#pragma unroll
            for (int p = 0; p < 4; p++)
                stg[p] = *(const bf16x8*)(kp + (size_t)(16 * p) * CK);
        } else {
            const bf16* vp = vg + ((size_t)b * NN + k0 + sv_q4) * CK + sv_chunk * 8;
#pragma unroll
            for (int p = 0; p < 4; p++)
                stg[p] = *(const bf16x8*)(vp + (size_t)p * CK);
        }
    };
    auto write_lds = [&]() {
        if (w < 4) {
#pragma unroll
            for (int p = 0; p < 4; p++) {
                int kr = sk_rowb + 16 * p;
                *(bf16x8*)(s_k + ((kr * 256 + sk_chunk * 16) ^ ((kr & 7) << 4))) = stg[p];
            }
        } else {
            int d0 = sv_chunk * 8;
#pragma unroll
            for (int i = 0; i < 8; i++) {
                bf16x4 pk = { stg[0][i], stg[1][i], stg[2][i], stg[3][i] };
                int d = d0 + i;
                *(bf16x4*)(s_vt + ((d * 128 + sv_q4 * 2) ^ (((d ^ (d >> 3)) & 7) << 4))) = pk;
            }
        }
    };

    issue_loads(kbeg);

    for (int k0 = kbeg; k0 < kend; k0 += 64) {
        __syncthreads();          // previous tile's compute done; LDS free
        write_lds();
        __syncthreads();          // staged tile visible
        if (k0 + 64 < kend) issue_loads(k0 + 64);

        // ---- S^T = K Q^T (Q pre-scaled): sa[j][qm], key = j*16+lg*4+r, q = lr
        f32x4 sa[4][2];
#pragma unroll
        for (int j = 0; j < 4; j++) {
            bf16x8 kf[4];
#pragma unroll
            for (int ks = 0; ks < 4; ks++) {
                int kr = j * 16 + lr;
                kf[ks] = *(const bf16x8*)(s_k + ((kr * 256 + ks * 64 + lg * 16) ^ ((kr & 7) << 4)));
            }
            sa[j][0] = (f32x4){0.f, 0.f, 0.f, 0.f};
            sa[j][1] = (f32x4){0.f, 0.f, 0.f, 0.f};
#pragma unroll
            for (int ks = 0; ks < 4; ks++) {
                sa[j][0] = __builtin_amdgcn_mfma_f32_16x16x32_bf16(kf[ks], qf[0][ks], sa[j][0], 0, 0, 0);
                sa[j][1] = __builtin_amdgcn_mfma_f32_16x16x32_bf16(kf[ks], qf[1][ks], sa[j][1], 0, 0, 0);
            }
        }

        // ---- online softmax, defer-max (THR=8)
        float pmax[2];
#pragma unroll
        for (int qm = 0; qm < 2; qm++) {
            float m0 = fmaxf(fmaxf(sa[0][qm][0], sa[0][qm][1]), fmaxf(sa[0][qm][2], sa[0][qm][3]));
            float m1 = fmaxf(fmaxf(sa[1][qm][0], sa[1][qm][1]), fmaxf(sa[1][qm][2], sa[1][qm][3]));
            float m2 = fmaxf(fmaxf(sa[2][qm][0], sa[2][qm][1]), fmaxf(sa[2][qm][2], sa[2][qm][3]));
            float m3 = fmaxf(fmaxf(sa[3][qm][0], sa[3][qm][1]), fmaxf(sa[3][qm][2], sa[3][qm][3]));
            pmax[qm] = fmaxf(fmaxf(m0, m1), fmaxf(m2, m3));
        }
        bool ok = (pmax[0] <= mrun[0] + 8.f) && (pmax[1] <= mrun[1] + 8.f);
        if (!__all(ok)) {
#pragma unroll
            for (int qm = 0; qm < 2; qm++) {
                float mx = pmax[qm];
                mx = fmaxf(mx, __shfl_xor(mx, 16));
                mx = fmaxf(mx, __shfl_xor(mx, 32));
                float mnew = fmaxf(mrun[qm], mx);
                float corr = exp2f((mrun[qm] - mnew) * L2E);
                mrun[qm] = mnew;
                lrun[qm] *= corr;
                float co[4];
#pragma unroll
                for (int r = 0; r < 4; r++)
                    co[r] = __shfl(corr, (lane & 48) | (lg * 4 + r));
#pragma unroll
                for (int dj = 0; dj < 8; dj++)
#pragma unroll
                    for (int r = 0; r < 4; r++) oacc[dj][qm][r] *= co[r];
            }
        }

        // ---- P = exp(S - m), pack to LDS; accumulate per-lane partial l
#pragma unroll
        for (int qm = 0; qm < 2; qm++) {
            float mL = mrun[qm] * L2E;
            float ps = 0.f;
#pragma unroll
            for (int j = 0; j < 4; j++) {
                float p0 = exp2f(sa[j][qm][0] * L2E - mL);
                float p1 = exp2f(sa[j][qm][1] * L2E - mL);
                float p2 = exp2f(sa[j][qm][2] * L2E - mL);
                float p3 = exp2f(sa[j][qm][3] * L2E - mL);
                ps += (p0 + p1) + (p2 + p3);
                bf16x4 pk = { (bf16)p0, (bf16)p1, (bf16)p2, (bf16)p3 };
                int q_local = qm * 16 + lr;
                *(bf16x4*)(s_pw + q_local * 80 + (j * 16 + lg * 4) * 2) = pk;
            }
            lrun[qm] += ps;
        }

        // ---- O += P V : oacc[dj][qm], q = lg*4+r, d = dj*16+lr
#pragma unroll
        for (int kc = 0; kc < 2; kc++) {
            bf16x8 pf[2];
#pragma unroll
            for (int qm = 0; qm < 2; qm++)
                pf[qm] = *(const bf16x8*)(s_pw + (qm * 16 + lr) * 80 + (kc * 32 + lg * 8) * 2);
#pragma unroll
            for (int dj = 0; dj < 8; dj++) {
                int d = dj * 16 + lr;
                bf16x8 vf = *(const bf16x8*)(s_vt + ((d * 128 + (kc * 32 + lg * 8) * 2) ^ (((d ^ (d >> 3)) & 7) << 4)));
                oacc[dj][0] = __builtin_amdgcn_mfma_f32_16x16x32_bf16(pf[0], vf, oacc[dj][0], 0, 0, 0);
                oacc[dj][1] = __builtin_amdgcn_mfma_f32_16x16x32_bf16(pf[1], vf, oacc[dj][1], 0, 0, 0);
            }
        }
    }

    // ---- epilogue: unnormalized O + (m, l) per row
    size_t obase = ((size_t)split * BB + b) * NN;
    int qbase = q0 + w * 32;
#pragma unroll
    for (int qm = 0; qm < 2; qm++) {
        float ls = lrun[qm];
        ls += __shfl_xor(ls, 16);
        ls += __shfl_xor(ls, 32);
        if (lg == 0) {
            Mw[obase + qbase + qm * 16 + lr] = mrun[qm];
            Lw[obase + qbase + qm * 16 + lr] = ls;
        }
#pragma unroll
        for (int dj = 0; dj < 8; dj++)
#pragma unroll
            for (int r = 0; r < 4; r++) {
                int q = qbase + qm * 16 + lg * 4 + r;
                Opart[(obase + q) * CK + dj * 16 + lr] = oacc[dj][qm][r];
            }
    }
}

// ---------------- Kernel 2b: combine KV-split partials ----------------
__global__ __launch_bounds__(256) void k_combine(
    const float* __restrict__ Opart, const float* __restrict__ Mw,
    const float* __restrict__ Lw, bf16* __restrict__ ao, int nsplit)
{
    const int t = threadIdx.x;
    const int b = blockIdx.y;
    const int r0 = blockIdx.x * 64;
    const int d4 = (t & 31) * 4;
#pragma unroll
    for (int p = 0; p < 8; p++) {
        int row = r0 + (t >> 5) + p * 8;
        size_t rbase = (size_t)b * NN + row;
        float M = -1e30f;
        for (int s = 0; s < nsplit; s++)
            M = fmaxf(M, Mw[((size_t)s * BB) * NN + rbase]);
        float L = 0.f;
        float4 acc = {0.f, 0.f, 0.f, 0.f};
        for (int s = 0; s < nsplit; s++) {
            size_t sb = ((size_t)s * BB) * NN + rbase;
            float wgt = __expf(Mw[sb] - M);
            L += Lw[sb] * wgt;
            float4 v = *(const float4*)(Opart + sb * CK + d4);
            acc.x += v.x * wgt; acc.y += v.y * wgt;
            acc.z += v.z * wgt; acc.w += v.w * wgt;
        }
        float inv = 1.f / L;
        bf16x4 o4 = { (bf16)(acc.x * inv), (bf16)(acc.y * inv),
                      (bf16)(acc.z * inv), (bf16)(acc.w * inv) };
        *(bf16x4*)(ao + rbase * CK + d4) = o4;
    }
}

// ---------------- Kernel 3: folded output projection + bias + residual ----------------
__global__ __launch_bounds__(256) void k_out(
    const float* __restrict__ x, const float* __restrict__ Wo, const float* __restrict__ bo,
    const bf16* __restrict__ ao, float* __restrict__ y)
{
    const int t = threadIdx.x;
    const int lane = t & 63, w = t >> 6;
    const int lr = lane & 15, lg = lane >> 4;
    const int n0 = blockIdx.x * 128;
    const int o0 = blockIdx.y * 64;
    const int b = blockIdx.z;

    __shared__ __align__(16) char s_w[64 * 256];
    __shared__ __align__(16) char s_a[128 * 256];

    {
        int c4 = (t & 31) * 4, rbase = t >> 5;
#pragma unroll
        for (int p = 0; p < 8; p++) {
            int row = rbase + p * 8;
            const float* wp = Wo + (size_t)(o0 + row) * C + c4;
            float4 a0 = *(const float4*)(wp);
            float4 a1 = *(const float4*)(wp + 128);
            float4 a2 = *(const float4*)(wp + 256);
            float4 a3 = *(const float4*)(wp + 384);
            bf16x4 r4 = { (bf16)(a0.x + a1.x + a2.x + a3.x), (bf16)(a0.y + a1.y + a2.y + a3.y),
                          (bf16)(a0.z + a1.z + a2.z + a3.z), (bf16)(a0.w + a1.w + a2.w + a3.w) };
            int off = (row * 256 + c4 * 2) ^ ((row & 7) << 4);
            *(bf16x4*)(s_w + off) = r4;
        }
    }
    {
        int chunk = t & 15, rbase = t >> 4;
#pragma unroll
        for (int p = 0; p < 8; p++) {
            int row = rbase + p * 16;
            bf16x8 v = *(const bf16x8*)(ao + ((size_t)b * NN + n0 + row) * CK + chunk * 8);
            int off = (row * 256 + chunk * 16) ^ ((row & 7) << 4);
            *(bf16x8*)(s_a + off) = v;
        }
    }
    __syncthreads();

    f32x4 acc[8];
#pragma unroll
    for (int j = 0; j < 8; j++) acc[j] = (f32x4){0.f, 0.f, 0.f, 0.f};
#pragma unroll
    for (int ks = 0; ks < 4; ks++) {
        int row = w * 16 + lr;
        int aoff = (row * 256 + (ks * 32 + lg * 8) * 2) ^ ((row & 7) << 4);
        bf16x8 wf = *(const bf16x8*)(s_w + aoff);
#pragma unroll
        for (int j = 0; j < 8; j++) {
            int nrow = j * 16 + lr;
            int boff = (nrow * 256 + (ks * 32 + lg * 8) * 2) ^ ((nrow & 7) << 4);
            bf16x8 af = *(const bf16x8*)(s_a + boff);
            acc[j] = __builtin_amdgcn_mfma_f32_16x16x32_bf16(wf, af, acc[j], 0, 0, 0);
        }
    }
#pragma unroll
    for (int j = 0; j < 8; j++) {
        int n = n0 + j * 16 + lr;
#pragma unroll
        for (int r = 0; r < 4; r++) {
            int o = o0 + w * 16 + lg * 4 + r;
            size_t idx = ((size_t)b * C + o) * NN + n;
            y[idx] = acc[j][r] + bo[o] + x[idx];
        }
    }
}

extern "C" void kernel_launch(void* const* d_in, const int* in_sizes, int n_in,
                              void* d_out, int out_size, void* d_ws, size_t ws_size,
                              hipStream_t stream)
{
    const float* x  = (const float*)d_in[0];
    const float* Wq = (const float*)d_in[1];
    const float* bq = (const float*)d_in[2];
    const float* Wk = (const float*)d_in[3];
    const float* bk = (const float*)d_in[4];
    const float* Wv = (const float*)d_in[5];
    const float* bv = (const float*)d_in[6];
    const float* Wo = (const float*)d_in[7];
    const float* bo = (const float*)d_in[8];
    float* y = (float*)d_out;

    const size_t qkv_elems = (size_t)3 * BB * NN * CK;   // bf16
    const size_t ao_elems  = (size_t)BB * NN * CK;       // bf16

    bf16* qkv = (bf16*)d_ws;
    bf16* ao  = qkv + qkv_elems;
    float* Opart = (float*)(ao + ao_elems);

    int nsplit = 4;
    {
        size_t fixed = (qkv_elems + ao_elems) * sizeof(bf16);
        size_t per_split = ((size_t)BB * NN * CK + 2 * (size_t)BB * NN) * sizeof(float);
        while (nsplit > 1 && fixed + (size_t)nsplit * per_split > ws_size) nsplit >>= 1;
    }
    float* Mw = Opart + (size_t)nsplit * BB * NN * CK;
    float* Lw = Mw + (size_t)nsplit * BB * NN;

    k_qkv<<<dim3(NN / 128, 3, BB), 256, 0, stream>>>(x, Wq, bq, Wk, bk, Wv, bv, qkv);
    k_attn<<<dim3(64 * nsplit, 1, 1), 512, 0, stream>>>(qkv, Opart, Mw, Lw, nsplit);
    k_combine<<<dim3(NN / 64, BB), 256, 0, stream>>>(Opart, Mw, Lw, ao, nsplit);
    k_out<<<dim3(NN / 128, C / 64, BB), 256, 0, stream>>>(x, Wo, bo, ao, y);
}